// Round 1
// baseline (217.139 us; speedup 1.0000x reference)
//
#include <hip/hip_runtime.h>

// 3D spatial correlation sampler, kernel_size=1, stride=1, pad=0, dil=1, patch=7
// in1,in2: [B=2, C=32, D=32, H=32, W=32] fp32
// out:     [B, 7,7,7, D,H,W] fp32
// out[b,pd,ph,pw,d,h,w] = sum_c in1[b,c,d,h,w] * in2[b,c,d+pd-3,h+ph-3,w+pw-3]
// (zero for OOB reads of in2)

#define BB 2
#define CC 32
#define DD 32
#define HH 32
#define WW 32
#define PP 7
#define RR 3
#define PLANE (HH * WW)          // 1024
#define CH_STRIDE (DD * HH * WW) // 32768

__global__ __launch_bounds__(256) void corr3d_kernel(
    const float* __restrict__ in1,
    const float* __restrict__ in2,
    float* __restrict__ out) {
    const int tid = threadIdx.x;
    int bi = blockIdx.x;
    const int off = bi % 49; bi /= 49;      // (pd,ph) fastest -> L2 sharing
    const int d2  = bi % 16; bi /= 16;
    const int b   = bi;                     // 0..1
    const int pd  = off / 7;
    const int ph  = off % 7;

    const int wb = tid & 3;                 // w-block 0..3
    const int w0 = wb << 3;                 // 0,8,16,24
    const int h  = (tid >> 2) & 31;
    const int d  = d2 * 2 + (tid >> 7);

    const int dz = d + pd - RR;
    const int hy = h + ph - RR;
    const bool pv = (unsigned)dz < DD;
    const bool rv = (unsigned)hy < HH;

    float acc[8][7];
#pragma unroll
    for (int i = 0; i < 8; ++i)
#pragma unroll
        for (int p = 0; p < 7; ++p) acc[i][p] = 0.f;

    if (pv && rv) {
        const float* p1 = in1 + ((size_t)b * CC * DD + d) * PLANE + h * WW + w0;
        const float* p2 = in2 + ((size_t)b * CC * DD + dz) * PLANE + hy * WW + (w0 - 4);
        const bool lv  = (wb != 0);  // left window block in-range
        const bool rvb = (wb != 3);  // right window block in-range

#pragma unroll 2
        for (int c = 0; c < CC; ++c) {
            const float4 a0 = *(const float4*)(p1);
            const float4 a1 = *(const float4*)(p1 + 4);
            const float4 z  = make_float4(0.f, 0.f, 0.f, 0.f);
            const float4 q0 = lv  ? *(const float4*)(p2)      : z;
            const float4 q1 =       *(const float4*)(p2 + 4);
            const float4 q2 =       *(const float4*)(p2 + 8);
            const float4 q3 = rvb ? *(const float4*)(p2 + 12) : z;

            const float a[8]   = {a0.x, a0.y, a0.z, a0.w, a1.x, a1.y, a1.z, a1.w};
            const float win[16] = {q0.x, q0.y, q0.z, q0.w,
                                   q1.x, q1.y, q1.z, q1.w,
                                   q2.x, q2.y, q2.z, q2.w,
                                   q3.x, q3.y, q3.z, q3.w};
#pragma unroll
            for (int i = 0; i < 8; ++i)
#pragma unroll
                for (int p = 0; p < 7; ++p)
                    acc[i][p] = fmaf(a[i], win[i + p + 1], acc[i][p]);

            p1 += CH_STRIDE;
            p2 += CH_STRIDE;
        }
    }

    float* po = out + (((size_t)(b * 49 + pd * 7 + ph)) * PP) * CH_STRIDE
                    + (size_t)d * PLANE + h * WW + w0;
#pragma unroll
    for (int p = 0; p < 7; ++p) {
        *(float4*)(po)     = make_float4(acc[0][p], acc[1][p], acc[2][p], acc[3][p]);
        *(float4*)(po + 4) = make_float4(acc[4][p], acc[5][p], acc[6][p], acc[7][p]);
        po += CH_STRIDE;
    }
}

extern "C" void kernel_launch(void* const* d_in, const int* in_sizes, int n_in,
                              void* d_out, int out_size, void* d_ws, size_t ws_size,
                              hipStream_t stream) {
    const float* in1 = (const float*)d_in[0];
    const float* in2 = (const float*)d_in[1];
    float* out = (float*)d_out;
    // grid: 49 offsets (fastest) x 16 d-pairs x 2 batches = 1568 blocks of 256
    dim3 grid(49 * 16 * 2);
    dim3 block(256);
    hipLaunchKernelGGL(corr3d_kernel, grid, block, 0, stream, in1, in2, out);
}